// Round 18
// baseline (263.404 us; speedup 1.0000x reference)
//
#include <hip/hip_runtime.h>
#include <hip/hip_bf16.h>
#include <math.h>

#define B_    8
#define T_    4096
#define CD    1024
#define DM    768
#define NH    12
#define DH    64
#define NQ    256
#define INNER 768
#define NKV   1536
#define MKV   (B_*T_)
#define EPS   1e-5f
#define SCALE 0.125f

typedef __attribute__((ext_vector_type(8))) short short8;
typedef __attribute__((ext_vector_type(4))) float f32x4;

__device__ __forceinline__ unsigned short f2bf(float f) {
  union { __hip_bfloat16 h; unsigned short u; } cv;
  cv.h = __float2bfloat16(f);
  return cv.u;
}

// ------ merged weight transposes: f32 [SR][SC] -> bf16 [SC][SR], z-indexed --
__global__ __launch_bounds__(256) void tbw_kernel(
    const float* __restrict__ s0, unsigned short* __restrict__ d0,
    const float* __restrict__ s1, unsigned short* __restrict__ d1,
    const float* __restrict__ s2, unsigned short* __restrict__ d2) {
  int z = blockIdx.z;
  const float* src; unsigned short* dst; int SR, SC;
  if (z == 0)      { src = s0; dst = d0; SR = CD;    SC = NKV; }
  else if (z == 1) { src = s1; dst = d1; SR = DM;    SC = INNER; }
  else             { src = s2; dst = d2; SR = INNER; SC = DM; }
  int k0 = blockIdx.x * 32, n0 = blockIdx.y * 32;
  if (k0 >= SR || n0 >= SC) return;
  __shared__ float tile[32][33];
  int tid = threadIdx.x;
  int r = tid >> 3, c4 = (tid & 7) * 4;
  float4 v = *reinterpret_cast<const float4*>(&src[(size_t)(k0 + r) * SC + n0 + c4]);
  tile[r][c4 + 0] = v.x; tile[r][c4 + 1] = v.y; tile[r][c4 + 2] = v.z; tile[r][c4 + 3] = v.w;
  __syncthreads();
  ushort4 o4;
  o4.x = f2bf(tile[c4 + 0][r]);
  o4.y = f2bf(tile[c4 + 1][r]);
  o4.z = f2bf(tile[c4 + 2][r]);
  o4.w = f2bf(tile[c4 + 3][r]);
  *reinterpret_cast<ushort4*>(&dst[(size_t)(n0 + r) * SR + k0 + c4]) = o4;
}

// ----------------------------- LN(query) -> bf16 ---------------------------
__global__ __launch_bounds__(256) void qln_kernel(
    const float* __restrict__ query, const float* __restrict__ lnw,
    const float* __restrict__ lnb, unsigned short* __restrict__ qn) {
  int row = blockIdx.x, tid = threadIdx.x;
  __shared__ float rbuf[256];
  const float* qr = query + (size_t)row * DM;
  float v0 = qr[tid], v1 = qr[tid + 256], v2 = qr[tid + 512];
  rbuf[tid] = v0 + v1 + v2;
  __syncthreads();
  for (int o = 128; o > 0; o >>= 1) { if (tid < o) rbuf[tid] += rbuf[tid + o]; __syncthreads(); }
  float mean = rbuf[0] * (1.f / 768.f);
  __syncthreads();
  float d0 = v0 - mean, d1 = v1 - mean, d2 = v2 - mean;
  rbuf[tid] = d0 * d0 + d1 * d1 + d2 * d2;
  __syncthreads();
  for (int o = 128; o > 0; o >>= 1) { if (tid < o) rbuf[tid] += rbuf[tid + o]; __syncthreads(); }
  float var = rbuf[0] * (1.f / 768.f);
  float rs = rsqrtf(var + EPS);
  unsigned short* dst = qn + (size_t)row * DM;
  dst[tid]       = f2bf(d0 * rs * lnw[tid]       + lnb[tid]);
  dst[tid + 256] = f2bf(d1 * rs * lnw[tid + 256] + lnb[tid + 256]);
  dst[tid + 512] = f2bf(d2 * rs * lnw[tid + 512] + lnb[tid + 512]);
}

// ---------------------------- LN(x) -> bf16, fused stats + normalize -------
__global__ __launch_bounds__(256) void xnorm_kernel(
    const float* __restrict__ x, const float* __restrict__ lnw,
    const float* __restrict__ lnb, unsigned short* __restrict__ xn) {
  int row = blockIdx.x, tid = threadIdx.x;
  float4 v = reinterpret_cast<const float4*>(x + (size_t)row * CD)[tid];
  float s  = v.x + v.y + v.z + v.w;
  float ss = v.x * v.x + v.y * v.y + v.z * v.z + v.w * v.w;
  #pragma unroll
  for (int o = 32; o > 0; o >>= 1) { s += __shfl_down(s, o); ss += __shfl_down(ss, o); }
  __shared__ float sm[8];
  int wid = tid >> 6, lane = tid & 63;
  if (lane == 0) { sm[wid] = s; sm[4 + wid] = ss; }
  __syncthreads();
  float S  = sm[0] + sm[1] + sm[2] + sm[3];
  float SS = sm[4] + sm[5] + sm[6] + sm[7];
  float m  = S * (1.f / 1024.f);
  float var = SS * (1.f / 1024.f) - m * m;
  float rs = rsqrtf(fmaxf(var, 0.f) + EPS);
  float4 wv = reinterpret_cast<const float4*>(lnw)[tid];
  float4 bv = reinterpret_cast<const float4*>(lnb)[tid];
  ushort4 o4;
  o4.x = f2bf((v.x - m) * rs * wv.x + bv.x);
  o4.y = f2bf((v.y - m) * rs * wv.y + bv.y);
  o4.z = f2bf((v.z - m) * rs * wv.z + bv.z);
  o4.w = f2bf((v.w - m) * rs * wv.w + bv.w);
  reinterpret_cast<ushort4*>(xn + (size_t)row * CD)[tid] = o4;
}

// ----------- generic 128x128 bf16 MFMA GEMM: C = A[M][K] @ Bt[N][K]^T ------
template <int MODE>
__global__ __launch_bounds__(256) void gemm128_kernel(
    const unsigned short* __restrict__ A, const unsigned short* __restrict__ Bt,
    void* __restrict__ Cout, int N, int K, int nN, float scale, int swz) {
  __shared__ __attribute__((aligned(16))) unsigned short As[128 * 64];
  __shared__ __attribute__((aligned(16))) unsigned short Bs[128 * 64];
  int tid = threadIdx.x;
  int w = tid >> 6, lane = tid & 63;
  int bid = blockIdx.x;
  int sw = swz ? ((bid & 7) * ((int)gridDim.x >> 3) + (bid >> 3)) : bid;
  int mt = sw / nN, nt = sw % nN;
  int m0 = mt * 128, n0 = nt * 128;

  int srow[4], skoff[4];
  #pragma unroll
  for (int i = 0; i < 4; ++i) {
    int L = w * 4096 + i * 1024 + lane * 16;
    int row = L >> 7;
    int slot = (L >> 4) & 7;
    srow[i] = row;
    skoff[i] = ((slot ^ (row & 7)) << 3);
  }

  f32x4 acc[4][4];
  #pragma unroll
  for (int m = 0; m < 4; ++m)
    #pragma unroll
    for (int n = 0; n < 4; ++n) acc[m][n] = (f32x4){0.f, 0.f, 0.f, 0.f};

  int wr = w >> 1, wc = w & 1;
  int l15 = lane & 15, l4 = lane >> 4;

  for (int t = 0; t < K / 64; ++t) {
    int k0 = t * 64;
    #pragma unroll
    for (int i = 0; i < 4; ++i) {
      __builtin_amdgcn_global_load_lds(
          (const __attribute__((address_space(1))) void*)(A + (size_t)(m0 + srow[i]) * K + k0 + skoff[i]),
          (__attribute__((address_space(3))) void*)(As + w * 2048 + i * 512 + lane * 8),
          16, 0, 0);
    }
    #pragma unroll
    for (int i = 0; i < 4; ++i) {
      __builtin_amdgcn_global_load_lds(
          (const __attribute__((address_space(1))) void*)(Bt + (size_t)(n0 + srow[i]) * K + k0 + skoff[i]),
          (__attribute__((address_space(3))) void*)(Bs + w * 2048 + i * 512 + lane * 8),
          16, 0, 0);
    }
    __syncthreads();
    #pragma unroll
    for (int kh = 0; kh < 2; ++kh) {
      short8 af[4], bf[4];
      #pragma unroll
      for (int m = 0; m < 4; ++m) {
        int row = wr * 64 + m * 16 + l15;
        int byte = row * 128 + (((l4 + 4 * kh) ^ (row & 7)) << 4);
        af[m] = *reinterpret_cast<const short8*>(reinterpret_cast<const char*>(As) + byte);
      }
      #pragma unroll
      for (int n = 0; n < 4; ++n) {
        int row = wc * 64 + n * 16 + l15;
        int byte = row * 128 + (((l4 + 4 * kh) ^ (row & 7)) << 4);
        bf[n] = *reinterpret_cast<const short8*>(reinterpret_cast<const char*>(Bs) + byte);
      }
      #pragma unroll
      for (int m = 0; m < 4; ++m)
        #pragma unroll
        for (int n = 0; n < 4; ++n)
          acc[m][n] = __builtin_amdgcn_mfma_f32_16x16x32_bf16(af[m], bf[n], acc[m][n], 0, 0, 0);
    }
    __syncthreads();
  }

  #pragma unroll
  for (int m = 0; m < 4; ++m) {
    int grow = m0 + wr * 64 + m * 16 + l4 * 4;
    #pragma unroll
    for (int n = 0; n < 4; ++n) {
      int gcol = n0 + wc * 64 + n * 16 + l15;
      #pragma unroll
      for (int r = 0; r < 4; ++r) {
        if (MODE == 0)
          ((unsigned short*)Cout)[(size_t)(grow + r) * N + gcol] = f2bf(acc[m][n][r] * scale);
        else
          ((float*)Cout)[(size_t)(grow + r) * N + gcol] = acc[m][n][r];
      }
    }
  }
}

// -------- kv GEMM: 256x256, 8 waves, dbuf, 2-phase (R10/R14: best) ---------
#define KBM 256
#define KBN 256
#define KBK 64
__global__ __launch_bounds__(512, 2) void kv_split_kernel(
    const unsigned short* __restrict__ xn, const unsigned short* __restrict__ wkvT,
    unsigned short* __restrict__ kvbK, unsigned short* __restrict__ vT) {
  __shared__ __attribute__((aligned(16))) unsigned short As[2][KBM * KBK];  // 64 KB
  __shared__ __attribute__((aligned(16))) unsigned short Bs[2][KBN * KBK];  // 64 KB
  int tid = threadIdx.x;
  int w = tid >> 6, lane = tid & 63;
  int wm = w >> 2, wn = w & 3;
  int l15 = lane & 15, l4 = lane >> 4;

  int bid = blockIdx.x;                      // 768 blocks, %8==0 -> bijective
  int sw = (bid & 7) * 96 + (bid >> 3);
  int mt = sw / (NKV / KBN), nt = sw % (NKV / KBN);
  int m0 = mt * KBM, n0 = nt * KBN;

  int srow[4], koff[4];
  #pragma unroll
  for (int i = 0; i < 4; ++i) {
    int r = i * 64 + (tid >> 3);
    srow[i] = r;
    koff[i] = (((tid & 7) ^ (r & 7)) << 3);
  }

  f32x4 acc[8][4];
  #pragma unroll
  for (int m = 0; m < 8; ++m)
    #pragma unroll
    for (int n = 0; n < 4; ++n) acc[m][n] = (f32x4){0.f, 0.f, 0.f, 0.f};

  #pragma unroll
  for (int i = 0; i < 4; ++i) {
    __builtin_amdgcn_global_load_lds(
        (const __attribute__((address_space(1))) void*)(xn + (size_t)(m0 + srow[i]) * CD + koff[i]),
        (__attribute__((address_space(3))) void*)(&As[0][0] + i * 4096 + tid * 8), 16, 0, 0);
    __builtin_amdgcn_global_load_lds(
        (const __attribute__((address_space(1))) void*)(wkvT + (size_t)(n0 + srow[i]) * CD + koff[i]),
        (__attribute__((address_space(3))) void*)(&Bs[0][0] + i * 4096 + tid * 8), 16, 0, 0);
  }
  __syncthreads();

  for (int t = 0; t < CD / KBK; ++t) {
    int cur = t & 1;
    if (t + 1 < CD / KBK) {
      int k0 = (t + 1) * KBK;
      #pragma unroll
      for (int i = 0; i < 4; ++i) {
        __builtin_amdgcn_global_load_lds(
            (const __attribute__((address_space(1))) void*)(xn + (size_t)(m0 + srow[i]) * CD + k0 + koff[i]),
            (__attribute__((address_space(3))) void*)(&As[cur ^ 1][0] + i * 4096 + tid * 8), 16, 0, 0);
        __builtin_amdgcn_global_load_lds(
            (const __attribute__((address_space(1))) void*)(wkvT + (size_t)(n0 + srow[i]) * CD + k0 + koff[i]),
            (__attribute__((address_space(3))) void*)(&Bs[cur ^ 1][0] + i * 4096 + tid * 8), 16, 0, 0);
      }
    }
    const char* Ab = reinterpret_cast<const char*>(&As[cur][0]);
    const char* Bb = reinterpret_cast<const char*>(&Bs[cur][0]);
    #pragma unroll
    for (int kh = 0; kh < 2; ++kh) {
      short8 bf[4];
      #pragma unroll
      for (int n = 0; n < 4; ++n) {
        int row = wn * 64 + n * 16 + l15;
        int byt = row * 128 + (((kh * 4 + l4) ^ (row & 7)) << 4);
        bf[n] = *reinterpret_cast<const short8*>(Bb + byt);
      }
      #pragma unroll
      for (int m = 0; m < 8; ++m) {
        int row = wm * 128 + m * 16 + l15;
        int byt = row * 128 + (((kh * 4 + l4) ^ (row & 7)) << 4);
        short8 af = *reinterpret_cast<const short8*>(Ab + byt);
        #pragma unroll
        for (int n = 0; n < 4; ++n)
          acc[m][n] = __builtin_amdgcn_mfma_f32_16x16x32_bf16(af, bf[n], acc[m][n], 0, 0, 0);
      }
    }
    __syncthreads();
  }

  if (nt < 3) {                                        // K block -> kvbK dense
    #pragma unroll
    for (int m = 0; m < 8; ++m) {
      int grow = m0 + wm * 128 + m * 16 + l4 * 4;
      #pragma unroll
      for (int n = 0; n < 4; ++n) {
        int gcol = nt * 256 + wn * 64 + n * 16 + l15;
        #pragma unroll
        for (int r = 0; r < 4; ++r)
          kvbK[(size_t)(grow + r) * INNER + gcol] = f2bf(acc[m][n][r]);
      }
    }
  } else {                                             // V block -> vT directly
    int b = m0 >> 12;
    int h = (nt - 3) * 4 + wn;
    #pragma unroll
    for (int m = 0; m < 8; ++m) {
      int j = (m0 & 4095) + wm * 128 + m * 16 + l4 * 4;
      #pragma unroll
      for (int n = 0; n < 4; ++n) {
        int d = n * 16 + l15;
        ushort4 o4;
        o4.x = f2bf(acc[m][n][0]); o4.y = f2bf(acc[m][n][1]);
        o4.z = f2bf(acc[m][n][2]); o4.w = f2bf(acc[m][n][3]);
        *reinterpret_cast<ushort4*>(&vT[((size_t)(b * NH + h) * DH + d) * T_ + j]) = o4;
      }
    }
  }
}

// ------- flash attention, bf16 MFMA, K/V dbuf + defer-max + T1 grid --------
__global__ __launch_bounds__(256) void attn_mfma_kernel(
    const unsigned short* __restrict__ qpb, const unsigned short* __restrict__ kvbK,
    const unsigned short* __restrict__ vT,
    float* __restrict__ pO, float* __restrict__ pM, float* __restrict__ pL) {
  int bh = blockIdx.x, kc = blockIdx.y, qt = blockIdx.z;
  int b = bh / NH, h = bh % NH;
  __shared__ __attribute__((aligned(16))) unsigned short Ks[2][4096];
  __shared__ __attribute__((aligned(16))) unsigned short Vs[2][4096];
  __shared__ __attribute__((aligned(16))) unsigned short Ps[4][1024];
  int tid = threadIdx.x;
  int w = tid >> 6, lane = tid & 63;
  int l15 = lane & 15, l4 = lane >> 4;

  short8 qf[2];
  {
    const unsigned short* qb = qpb + (size_t)(qt * 64 + w * 16 + l15) * INNER + h * DH;
    qf[0] = *reinterpret_cast<const short8*>(qb + l4 * 8);
    qf[1] = *reinterpret_cast<const short8*>(qb + 32 + l4 * 8);
  }

  int srow0 = w * 16 + (lane >> 3);
  int srow1 = srow0 + 8;
  int koff0 = (((lane & 7) ^ (srow0 & 7)) << 3);
  int koff1 = (((lane & 7) ^ (srow1 & 7)) << 3);

  const size_t kbase = ((size_t)b * T_) * INNER + h * DH;
  const size_t vbase = ((size_t)bh * DH) * T_;

  auto stageKV = [&](int kt, int d) {
    int j0 = kc * 2048 + kt * 64;
    __builtin_amdgcn_global_load_lds(
        (const __attribute__((address_space(1))) void*)(kvbK + kbase + (size_t)(j0 + srow0) * INNER + koff0),
        (__attribute__((address_space(3))) void*)(&Ks[d][0] + w * 1024 + lane * 8), 16, 0, 0);
    __builtin_amdgcn_global_load_lds(
        (const __attribute__((address_space(1))) void*)(kvbK + kbase + (size_t)(j0 + srow1) * INNER + koff1),
        (__attribute__((address_space(3))) void*)(&Ks[d][0] + w * 1024 + 512 + lane * 8), 16, 0, 0);
    __builtin_amdgcn_global_load_lds(
        (const __attribute__((address_space(1))) void*)(vT + vbase + (size_t)srow0 * T_ + j0 + koff0),
        (__attribute__((address_space(3))) void*)(&Vs[d][0] + w * 1024 + lane * 8), 16, 0, 0);
    __builtin_amdgcn_global_load_lds(
        (const __attribute__((address_space(1))) void*)(vT + vbase + (size_t)srow1 * T_ + j0 + koff1),
        (__attribute__((address_space(3))) void*)(&Vs[d][0] + w * 1024 + 512 + lane * 8), 16, 0, 0);
  };

  f32x4 o[4];
  #pragma unroll
  for (int i = 0; i < 4; ++i) o[i] = (f32x4){0.f, 0.f, 0.f, 0.f};
  float m_run = -1e30f, l_run = 0.f;

  stageKV(0, 0);

  for (int kt = 0; kt < 32; ++kt) {
    int cur = kt & 1;
    if (kt + 1 < 32) {
      stageKV(kt + 1, cur ^ 1);
      asm volatile("s_waitcnt vmcnt(4)" ::: "memory");
    } else {
      asm volatile("s_waitcnt vmcnt(0)" ::: "memory");
    }
    __builtin_amdgcn_s_barrier();
    __builtin_amdgcn_sched_barrier(0);

    const char* Kb = reinterpret_cast<const char*>(&Ks[cur][0]);
    const char* Vb = reinterpret_cast<const char*>(&Vs[cur][0]);

    f32x4 st[4];
    __builtin_amdgcn_s_setprio(1);
    #pragma unroll
    for (int sub = 0; sub < 4; ++sub) {
      st[sub] = (f32x4){0.f, 0.f, 0.f, 0.f};
      #pragma unroll
      for (int hf = 0; hf < 2; ++hf) {
        int row = sub * 16 + l15;
        int byt = row * 128 + (((l4 + 4 * hf) ^ (row & 7)) << 4);
        short8 kf = *reinterpret_cast<const short8*>(Kb + byt);
        st[sub] = __builtin_amdgcn_mfma_f32_16x16x32_bf16(kf, qf[hf], st[sub], 0, 0, 0);
      }
    }
    __builtin_amdgcn_s_setprio(0);

    float tmax = -1e30f;
    #pragma unroll
    for (int sub = 0; sub < 4; ++sub)
      #pragma unroll
      for (int r = 0; r < 4; ++r) tmax = fmaxf(tmax, st[sub][r]);
    tmax = fmaxf(tmax, __shfl_xor(tmax, 16));
    tmax = fmaxf(tmax, __shfl_xor(tmax, 32));

    if (__ballot(tmax > m_run + 8.f)) {
      float m_new = fmaxf(m_run, tmax);
      float alpha = __expf(m_run - m_new);
      float ao[4];
      #pragma unroll
      for (int r = 0; r < 4; ++r) ao[r] = __shfl(alpha, (l4 << 2) | r);
      #pragma unroll
      for (int ds = 0; ds < 4; ++ds)
        #pragma unroll
        for (int r = 0; r < 4; ++r) o[ds][r] *= ao[r];
      l_run *= alpha;
      m_run = m_new;
    }

    float psum = 0.f;
    #pragma unroll
    for (int sub = 0; sub < 4; ++sub) {
      float p0 = __expf(st[sub][0] - m_run);
      float p1 = __expf(st[sub][1] - m_run);
      float p2 = __expf(st[sub][2] - m_run);
      float p3 = __expf(st[sub][3] - m_run);
      psum += (p0 + p1) + (p2 + p3);
      unsigned int u0 = (unsigned int)f2bf(p0) | ((unsigned int)f2bf(p1) << 16);
      unsigned int u1 = (unsigned int)f2bf(p2) | ((unsigned int)f2bf(p3) << 16);
      int slot = (sub * 2 + (l4 >> 1)) ^ (l15 & 7);
      int byt = l15 * 128 + (slot << 4) + (l4 & 1) * 8;
      uint2 uv; uv.x = u0; uv.y = u1;
      *reinterpret_cast<uint2*>(reinterpret_cast<char*>(Ps[w]) + byt) = uv;
    }
    psum += __shfl_xor(psum, 16);
    psum += __shfl_xor(psum, 32);
    l_run += psum;

    short8 pa[2];
    #pragma unroll
    for (int hf = 0; hf < 2; ++hf) {
      int byt = l15 * 128 + ((((hf << 2) + l4) ^ (l15 & 7)) << 4);
      pa[hf] = *reinterpret_cast<const short8*>(reinterpret_cast<const char*>(Ps[w]) + byt);
    }
    __builtin_amdgcn_s_setprio(1);
    #pragma unroll
    for (int ds = 0; ds < 4; ++ds) {
      #pragma unroll
      for (int hf = 0; hf < 2; ++hf) {
        int row = ds * 16 + l15;
        int byt = row * 128 + (((l4 + 4 * hf) ^ (row & 7)) << 4);
        short8 vf = *reinterpret_cast<const short8*>(Vb + byt);
        o[ds] = __builtin_amdgcn_mfma_f32_16x16x32_bf16(pa[hf], vf, o[ds], 0, 0, 0);
      }
    }
    __builtin_amdgcn_s_setprio(0);
    __builtin_amdgcn_s_barrier();
    __builtin_amdgcn_sched_barrier(0);
  }

  int pidx = bh * 2 + kc;
  int qrow0 = qt * 64 + w * 16;
  if (l4 == 0) {
    pM[(size_t)pidx * NQ + qrow0 + l15] = m_run;
    pL[(size_t)pidx * NQ + qrow0 + l15] = l_run;
  }
  #pragma unroll
  for (int ds = 0; ds < 4; ++ds)
    #pragma unroll
    for (int r = 0; r < 4; ++r)
      pO[((size_t)pidx * NQ + qrow0 + l4 * 4 + r) * DH + ds * 16 + l15] = o[ds][r];
}

// ------ fused combine + out GEMM: out = combine(pO,pM,pL) @ WoutT^T --------
// M=2048, N=768, K=768. K-tile 64 == DH, so K-tile t == head t: combine
// weights (w1,w2,1/L) are per-(row,t) scalars. A is reg-staged (combine +
// bf16 pack) into the same XOR-swizzled LDS layout the gemm128 A-read uses.
__global__ __launch_bounds__(256) void outfuse_kernel(
    const float* __restrict__ pO, const float* __restrict__ pM,
    const float* __restrict__ pL, const unsigned short* __restrict__ WoutT,
    float* __restrict__ out) {
  __shared__ __attribute__((aligned(16))) unsigned short As[128 * 64];
  __shared__ __attribute__((aligned(16))) unsigned short Bs[128 * 64];
  int tid = threadIdx.x;
  int w = tid >> 6, lane = tid & 63;
  int bid = blockIdx.x;                       // 96 blocks, %8==0 -> bijective
  int sw = (bid & 7) * 12 + (bid >> 3);
  int mt = sw / 6, nt = sw % 6;
  int m0 = mt * 128, n0 = nt * 128;

  int srow[4], skoff[4];
  #pragma unroll
  for (int i = 0; i < 4; ++i) {
    int L = w * 4096 + i * 1024 + lane * 16;
    int row = L >> 7;
    int slot = (L >> 4) & 7;
    srow[i] = row;
    skoff[i] = ((slot ^ (row & 7)) << 3);
  }

  f32x4 acc[4][4];
  #pragma unroll
  for (int m = 0; m < 4; ++m)
    #pragma unroll
    for (int n = 0; n < 4; ++n) acc[m][n] = (f32x4){0.f, 0.f, 0.f, 0.f};

  int wr = w >> 1, wc = w & 1;
  int l15 = lane & 15, l4 = lane >> 4;

  for (int t = 0; t < NH; ++t) {              // K-tile == head
    // A: reg-staged fused combine. Thread covers 4 (row, slot) pairs.
    #pragma unroll
    for (int i = 0; i < 4; ++i) {
      int lin = i * 256 + tid;
      int r = lin >> 3, sl = lin & 7;
      int gr = m0 + r;
      int b = gr >> 8, q = gr & 255;
      size_t i0 = ((size_t)(b * NH + t) * 2) * NQ + q;
      size_t i1 = i0 + NQ;
      float m1 = pM[i0], m2 = pM[i1], l1 = pL[i0], l2 = pL[i1];
      float Mx = fmaxf(m1, m2);
      float w1 = __expf(m1 - Mx), w2 = __expf(m2 - Mx);
      float invL = 1.f / (l1 * w1 + l2 * w2);
      w1 *= invL; w2 *= invL;
      const float* p0 = pO + i0 * DH + sl * 8;
      const float* p1 = pO + i1 * DH + sl * 8;
      float4 a0 = *reinterpret_cast<const float4*>(p0);
      float4 a1 = *reinterpret_cast<const float4*>(p0 + 4);
      float4 b0 = *reinterpret_cast<const float4*>(p1);
      float4 b1 = *reinterpret_cast<const float4*>(p1 + 4);
      short8 v8;
      v8[0] = (short)f2bf(a0.x * w1 + b0.x * w2);
      v8[1] = (short)f2bf(a0.y * w1 + b0.y * w2);
      v8[2] = (short)f2bf(a0.z * w1 + b0.z * w2);
      v8[3] = (short)f2bf(a0.w * w1 + b0.w * w2);
      v8[4] = (short)f2bf(a1.x * w1 + b1.x * w2);
      v8[5] = (short)f2bf(a1.y * w1 + b1.y * w2);
      v8[6] = (short)f2bf(a1.z * w1 + b1.z * w2);
      v8[7] = (short)f2bf(a1.w * w1 + b1.w * w2);
      *reinterpret_cast<short8*>(reinterpret_cast<char*>(As) +
                                 r * 128 + ((sl ^ (r & 7)) << 4)) = v8;
    }
    // B: global_load_lds from WoutT (cols = head t dims)
    int k0 = t * 64;
    #pragma unroll
    for (int i = 0; i < 4; ++i) {
      __builtin_amdgcn_global_load_lds(
          (const __attribute__((address_space(1))) void*)(WoutT + (size_t)(n0 + srow[i]) * INNER + k0 + skoff[i]),
          (__attribute__((address_space(3))) void*)(Bs + w * 2048 + i * 512 + lane * 8),
          16, 0, 0);
    }
    __syncthreads();
    #pragma unroll
    for (int kh = 0; kh < 2; ++kh) {
      short8 af[4], bf[4];
      #pragma unroll
      for (int m = 0; m < 4; ++m) {
        int row = wr * 64 + m * 16 + l15;
        int byte = row * 128 + (((l4 + 4 * kh) ^ (row & 7)) << 4);
        af[m] = *reinterpret_cast<const short8*>(reinterpret_cast<const char*>(As) + byte);
      }
      #pragma unroll
      for (int n = 0; n < 4; ++n) {
        int row = wc * 64 + n * 16 + l15;
        int byte = row * 128 + (((l4 + 4 * kh) ^ (row & 7)) << 4);
        bf[n] = *reinterpret_cast<const short8*>(reinterpret_cast<const char*>(Bs) + byte);
      }
      #pragma unroll
      for (int m = 0; m < 4; ++m)
        #pragma unroll
        for (int n = 0; n < 4; ++n)
          acc[m][n] = __builtin_amdgcn_mfma_f32_16x16x32_bf16(af[m], bf[n], acc[m][n], 0, 0, 0);
    }
    __syncthreads();
  }

  #pragma unroll
  for (int m = 0; m < 4; ++m) {
    int grow = m0 + wr * 64 + m * 16 + l4 * 4;
    #pragma unroll
    for (int n = 0; n < 4; ++n) {
      int gcol = n0 + wc * 64 + n * 16 + l15;
      #pragma unroll
      for (int r = 0; r < 4; ++r)
        out[(size_t)(grow + r) * DM + gcol] = acc[m][n][r];
    }
  }
}

// ---------------------------------------------------------------------------
extern "C" void kernel_launch(void* const* d_in, const int* in_sizes, int n_in,
                              void* d_out, int out_size, void* d_ws, size_t ws_size,
                              hipStream_t stream) {
  const float* x      = (const float*)d_in[0];
  const float* query  = (const float*)d_in[1];
  const float* ln_q_w = (const float*)d_in[2];
  const float* ln_q_b = (const float*)d_in[3];
  const float* ln_k_w = (const float*)d_in[4];
  const float* ln_k_b = (const float*)d_in[5];
  const float* Wq     = (const float*)d_in[6];
  const float* Wkv    = (const float*)d_in[7];
  const float* Wout   = (const float*)d_in[8];
  float* out = (float*)d_out;

  unsigned short* qpb   = (unsigned short*)d_ws;              // 196608
  unsigned short* xn    = qpb + (size_t)NQ * INNER;           // 33554432
  unsigned short* wkvT  = xn + (size_t)MKV * CD;              // 1572864
  unsigned short* kvbK  = wkvT + (size_t)NKV * CD;            // 25165824
  unsigned short* vT    = kvbK + (size_t)MKV * INNER;         // 25165824
  float* pO    = (float*)(vT + (size_t)MKV * INNER);          // 3145728 f
  float* pM    = pO + (size_t)B_ * NH * 2 * NQ * DH;          // 49152 f
  float* pL    = pM + (size_t)B_ * NH * 2 * NQ;               // 49152 f
  unsigned short* qn    = (unsigned short*)(pL + (size_t)B_ * NH * 2 * NQ);  // 196608
  unsigned short* WqT   = qn + (size_t)NQ * DM;               // 589824
  unsigned short* WoutT = WqT + (size_t)DM * INNER;           // 589824

  hipLaunchKernelGGL(tbw_kernel, dim3(CD / 32, NKV / 32, 3), dim3(256), 0, stream,
                     Wkv, wkvT, Wq, WqT, Wout, WoutT);
  hipLaunchKernelGGL(qln_kernel, dim3(NQ), dim3(256), 0, stream,
                     query, ln_q_w, ln_q_b, qn);
  hipLaunchKernelGGL((gemm128_kernel<0>), dim3((NQ / 128) * (INNER / 128)), dim3(256), 0, stream,
                     qn, WqT, (void*)qpb, INNER, DM, INNER / 128, SCALE, 0);
  hipLaunchKernelGGL(xnorm_kernel, dim3(MKV), dim3(256), 0, stream,
                     x, ln_k_w, ln_k_b, xn);
  hipLaunchKernelGGL(kv_split_kernel, dim3((MKV / KBM) * (NKV / KBN)), dim3(512), 0, stream,
                     xn, wkvT, kvbK, vT);
  hipLaunchKernelGGL(attn_mfma_kernel, dim3(B_ * NH, 2, 4), dim3(256), 0, stream,
                     qpb, kvbK, vT, pO, pM, pL);
  hipLaunchKernelGGL(outfuse_kernel, dim3((B_ * NQ / 128) * (DM / 128)), dim3(256), 0, stream,
                     pO, pM, pL, WoutT, out);
}

// Round 19
// 254.654 us; speedup vs baseline: 1.0344x; 1.0344x over previous
//
#include <hip/hip_runtime.h>
#include <hip/hip_bf16.h>
#include <math.h>

#define B_    8
#define T_    4096
#define CD    1024
#define DM    768
#define NH    12
#define DH    64
#define NQ    256
#define INNER 768
#define NKV   1536
#define MKV   (B_*T_)
#define EPS   1e-5f
#define SCALE 0.125f

typedef __attribute__((ext_vector_type(8))) short short8;
typedef __attribute__((ext_vector_type(4))) float f32x4;

__device__ __forceinline__ unsigned short f2bf(float f) {
  union { __hip_bfloat16 h; unsigned short u; } cv;
  cv.h = __float2bfloat16(f);
  return cv.u;
}

// ------ merged weight transposes: f32 [SR][SC] -> bf16 [SC][SR], z-indexed --
__global__ __launch_bounds__(256) void tbw_kernel(
    const float* __restrict__ s0, unsigned short* __restrict__ d0,
    const float* __restrict__ s1, unsigned short* __restrict__ d1,
    const float* __restrict__ s2, unsigned short* __restrict__ d2) {
  int z = blockIdx.z;
  const float* src; unsigned short* dst; int SR, SC;
  if (z == 0)      { src = s0; dst = d0; SR = CD;    SC = NKV; }
  else if (z == 1) { src = s1; dst = d1; SR = DM;    SC = INNER; }
  else             { src = s2; dst = d2; SR = INNER; SC = DM; }
  int k0 = blockIdx.x * 32, n0 = blockIdx.y * 32;
  if (k0 >= SR || n0 >= SC) return;
  __shared__ float tile[32][33];
  int tid = threadIdx.x;
  int r = tid >> 3, c4 = (tid & 7) * 4;
  float4 v = *reinterpret_cast<const float4*>(&src[(size_t)(k0 + r) * SC + n0 + c4]);
  tile[r][c4 + 0] = v.x; tile[r][c4 + 1] = v.y; tile[r][c4 + 2] = v.z; tile[r][c4 + 3] = v.w;
  __syncthreads();
  ushort4 o4;
  o4.x = f2bf(tile[c4 + 0][r]);
  o4.y = f2bf(tile[c4 + 1][r]);
  o4.z = f2bf(tile[c4 + 2][r]);
  o4.w = f2bf(tile[c4 + 3][r]);
  *reinterpret_cast<ushort4*>(&dst[(size_t)(n0 + r) * SR + k0 + c4]) = o4;
}

// ----------------------------- LN(query) -> bf16 ---------------------------
__global__ __launch_bounds__(256) void qln_kernel(
    const float* __restrict__ query, const float* __restrict__ lnw,
    const float* __restrict__ lnb, unsigned short* __restrict__ qn) {
  int row = blockIdx.x, tid = threadIdx.x;
  __shared__ float rbuf[256];
  const float* qr = query + (size_t)row * DM;
  float v0 = qr[tid], v1 = qr[tid + 256], v2 = qr[tid + 512];
  rbuf[tid] = v0 + v1 + v2;
  __syncthreads();
  for (int o = 128; o > 0; o >>= 1) { if (tid < o) rbuf[tid] += rbuf[tid + o]; __syncthreads(); }
  float mean = rbuf[0] * (1.f / 768.f);
  __syncthreads();
  float d0 = v0 - mean, d1 = v1 - mean, d2 = v2 - mean;
  rbuf[tid] = d0 * d0 + d1 * d1 + d2 * d2;
  __syncthreads();
  for (int o = 128; o > 0; o >>= 1) { if (tid < o) rbuf[tid] += rbuf[tid + o]; __syncthreads(); }
  float var = rbuf[0] * (1.f / 768.f);
  float rs = rsqrtf(var + EPS);
  unsigned short* dst = qn + (size_t)row * DM;
  dst[tid]       = f2bf(d0 * rs * lnw[tid]       + lnb[tid]);
  dst[tid + 256] = f2bf(d1 * rs * lnw[tid + 256] + lnb[tid + 256]);
  dst[tid + 512] = f2bf(d2 * rs * lnw[tid + 512] + lnb[tid + 512]);
}

// ---------------------------- LN(x) -> bf16, fused stats + normalize -------
__global__ __launch_bounds__(256) void xnorm_kernel(
    const float* __restrict__ x, const float* __restrict__ lnw,
    const float* __restrict__ lnb, unsigned short* __restrict__ xn) {
  int row = blockIdx.x, tid = threadIdx.x;
  float4 v = reinterpret_cast<const float4*>(x + (size_t)row * CD)[tid];
  float s  = v.x + v.y + v.z + v.w;
  float ss = v.x * v.x + v.y * v.y + v.z * v.z + v.w * v.w;
  #pragma unroll
  for (int o = 32; o > 0; o >>= 1) { s += __shfl_down(s, o); ss += __shfl_down(ss, o); }
  __shared__ float sm[8];
  int wid = tid >> 6, lane = tid & 63;
  if (lane == 0) { sm[wid] = s; sm[4 + wid] = ss; }
  __syncthreads();
  float S  = sm[0] + sm[1] + sm[2] + sm[3];
  float SS = sm[4] + sm[5] + sm[6] + sm[7];
  float m  = S * (1.f / 1024.f);
  float var = SS * (1.f / 1024.f) - m * m;
  float rs = rsqrtf(fmaxf(var, 0.f) + EPS);
  float4 wv = reinterpret_cast<const float4*>(lnw)[tid];
  float4 bv = reinterpret_cast<const float4*>(lnb)[tid];
  ushort4 o4;
  o4.x = f2bf((v.x - m) * rs * wv.x + bv.x);
  o4.y = f2bf((v.y - m) * rs * wv.y + bv.y);
  o4.z = f2bf((v.z - m) * rs * wv.z + bv.z);
  o4.w = f2bf((v.w - m) * rs * wv.w + bv.w);
  reinterpret_cast<ushort4*>(xn + (size_t)row * CD)[tid] = o4;
}

// ----------- generic 128x128 bf16 MFMA GEMM: C = A[M][K] @ Bt[N][K]^T ------
template <int MODE>
__global__ __launch_bounds__(256) void gemm128_kernel(
    const unsigned short* __restrict__ A, const unsigned short* __restrict__ Bt,
    void* __restrict__ Cout, int N, int K, int nN, float scale, int swz) {
  __shared__ __attribute__((aligned(16))) unsigned short As[128 * 64];
  __shared__ __attribute__((aligned(16))) unsigned short Bs[128 * 64];
  int tid = threadIdx.x;
  int w = tid >> 6, lane = tid & 63;
  int bid = blockIdx.x;
  int sw = swz ? ((bid & 7) * ((int)gridDim.x >> 3) + (bid >> 3)) : bid;
  int mt = sw / nN, nt = sw % nN;
  int m0 = mt * 128, n0 = nt * 128;

  int srow[4], skoff[4];
  #pragma unroll
  for (int i = 0; i < 4; ++i) {
    int L = w * 4096 + i * 1024 + lane * 16;
    int row = L >> 7;
    int slot = (L >> 4) & 7;
    srow[i] = row;
    skoff[i] = ((slot ^ (row & 7)) << 3);
  }

  f32x4 acc[4][4];
  #pragma unroll
  for (int m = 0; m < 4; ++m)
    #pragma unroll
    for (int n = 0; n < 4; ++n) acc[m][n] = (f32x4){0.f, 0.f, 0.f, 0.f};

  int wr = w >> 1, wc = w & 1;
  int l15 = lane & 15, l4 = lane >> 4;

  for (int t = 0; t < K / 64; ++t) {
    int k0 = t * 64;
    #pragma unroll
    for (int i = 0; i < 4; ++i) {
      __builtin_amdgcn_global_load_lds(
          (const __attribute__((address_space(1))) void*)(A + (size_t)(m0 + srow[i]) * K + k0 + skoff[i]),
          (__attribute__((address_space(3))) void*)(As + w * 2048 + i * 512 + lane * 8),
          16, 0, 0);
    }
    #pragma unroll
    for (int i = 0; i < 4; ++i) {
      __builtin_amdgcn_global_load_lds(
          (const __attribute__((address_space(1))) void*)(Bt + (size_t)(n0 + srow[i]) * K + k0 + skoff[i]),
          (__attribute__((address_space(3))) void*)(Bs + w * 2048 + i * 512 + lane * 8),
          16, 0, 0);
    }
    __syncthreads();
    #pragma unroll
    for (int kh = 0; kh < 2; ++kh) {
      short8 af[4], bf[4];
      #pragma unroll
      for (int m = 0; m < 4; ++m) {
        int row = wr * 64 + m * 16 + l15;
        int byte = row * 128 + (((l4 + 4 * kh) ^ (row & 7)) << 4);
        af[m] = *reinterpret_cast<const short8*>(reinterpret_cast<const char*>(As) + byte);
      }
      #pragma unroll
      for (int n = 0; n < 4; ++n) {
        int row = wc * 64 + n * 16 + l15;
        int byte = row * 128 + (((l4 + 4 * kh) ^ (row & 7)) << 4);
        bf[n] = *reinterpret_cast<const short8*>(reinterpret_cast<const char*>(Bs) + byte);
      }
      #pragma unroll
      for (int m = 0; m < 4; ++m)
        #pragma unroll
        for (int n = 0; n < 4; ++n)
          acc[m][n] = __builtin_amdgcn_mfma_f32_16x16x32_bf16(af[m], bf[n], acc[m][n], 0, 0, 0);
    }
    __syncthreads();
  }

  #pragma unroll
  for (int m = 0; m < 4; ++m) {
    int grow = m0 + wr * 64 + m * 16 + l4 * 4;
    #pragma unroll
    for (int n = 0; n < 4; ++n) {
      int gcol = n0 + wc * 64 + n * 16 + l15;
      #pragma unroll
      for (int r = 0; r < 4; ++r) {
        if (MODE == 0)
          ((unsigned short*)Cout)[(size_t)(grow + r) * N + gcol] = f2bf(acc[m][n][r] * scale);
        else
          ((float*)Cout)[(size_t)(grow + r) * N + gcol] = acc[m][n][r];
      }
    }
  }
}

// -------- kv GEMM: 256x256, 8 waves, dbuf, 2-phase core --------------------
// K-blocks (nt<3) write dense kvbK; V-blocks (nt>=3) transpose through
// XOR-swizzled LDS (phys = off ^ ((d&7)<<4), both write & read sides) and
// stream vT out as contiguous 16B stores.
#define KBM 256
#define KBN 256
#define KBK 64
__global__ __launch_bounds__(512, 2) void kv_split_kernel(
    const unsigned short* __restrict__ xn, const unsigned short* __restrict__ wkvT,
    unsigned short* __restrict__ kvbK, unsigned short* __restrict__ vT) {
  __shared__ __attribute__((aligned(16))) unsigned short As[2][KBM * KBK];  // 64 KB
  __shared__ __attribute__((aligned(16))) unsigned short Bs[2][KBN * KBK];  // 64 KB
  int tid = threadIdx.x;
  int w = tid >> 6, lane = tid & 63;
  int wm = w >> 2, wn = w & 3;
  int l15 = lane & 15, l4 = lane >> 4;

  int bid = blockIdx.x;                      // 768 blocks, %8==0 -> bijective
  int sw = (bid & 7) * 96 + (bid >> 3);
  int mt = sw / (NKV / KBN), nt = sw % (NKV / KBN);
  int m0 = mt * KBM, n0 = nt * KBN;

  int srow[4], koff[4];
  #pragma unroll
  for (int i = 0; i < 4; ++i) {
    int r = i * 64 + (tid >> 3);
    srow[i] = r;
    koff[i] = (((tid & 7) ^ (r & 7)) << 3);
  }

  f32x4 acc[8][4];
  #pragma unroll
  for (int m = 0; m < 8; ++m)
    #pragma unroll
    for (int n = 0; n < 4; ++n) acc[m][n] = (f32x4){0.f, 0.f, 0.f, 0.f};

  #pragma unroll
  for (int i = 0; i < 4; ++i) {
    __builtin_amdgcn_global_load_lds(
        (const __attribute__((address_space(1))) void*)(xn + (size_t)(m0 + srow[i]) * CD + koff[i]),
        (__attribute__((address_space(3))) void*)(&As[0][0] + i * 4096 + tid * 8), 16, 0, 0);
    __builtin_amdgcn_global_load_lds(
        (const __attribute__((address_space(1))) void*)(wkvT + (size_t)(n0 + srow[i]) * CD + koff[i]),
        (__attribute__((address_space(3))) void*)(&Bs[0][0] + i * 4096 + tid * 8), 16, 0, 0);
  }
  __syncthreads();

  for (int t = 0; t < CD / KBK; ++t) {
    int cur = t & 1;
    if (t + 1 < CD / KBK) {
      int k0 = (t + 1) * KBK;
      #pragma unroll
      for (int i = 0; i < 4; ++i) {
        __builtin_amdgcn_global_load_lds(
            (const __attribute__((address_space(1))) void*)(xn + (size_t)(m0 + srow[i]) * CD + k0 + koff[i]),
            (__attribute__((address_space(3))) void*)(&As[cur ^ 1][0] + i * 4096 + tid * 8), 16, 0, 0);
        __builtin_amdgcn_global_load_lds(
            (const __attribute__((address_space(1))) void*)(wkvT + (size_t)(n0 + srow[i]) * CD + k0 + koff[i]),
            (__attribute__((address_space(3))) void*)(&Bs[cur ^ 1][0] + i * 4096 + tid * 8), 16, 0, 0);
      }
    }
    const char* Ab = reinterpret_cast<const char*>(&As[cur][0]);
    const char* Bb = reinterpret_cast<const char*>(&Bs[cur][0]);
    #pragma unroll
    for (int kh = 0; kh < 2; ++kh) {
      short8 bf[4];
      #pragma unroll
      for (int n = 0; n < 4; ++n) {
        int row = wn * 64 + n * 16 + l15;
        int byt = row * 128 + (((kh * 4 + l4) ^ (row & 7)) << 4);
        bf[n] = *reinterpret_cast<const short8*>(Bb + byt);
      }
      #pragma unroll
      for (int m = 0; m < 8; ++m) {
        int row = wm * 128 + m * 16 + l15;
        int byt = row * 128 + (((kh * 4 + l4) ^ (row & 7)) << 4);
        short8 af = *reinterpret_cast<const short8*>(Ab + byt);
        #pragma unroll
        for (int n = 0; n < 4; ++n)
          acc[m][n] = __builtin_amdgcn_mfma_f32_16x16x32_bf16(af, bf[n], acc[m][n], 0, 0, 0);
      }
    }
    __syncthreads();
  }

  if (nt < 3) {                                        // K block -> kvbK dense
    #pragma unroll
    for (int m = 0; m < 8; ++m) {
      int grow = m0 + wm * 128 + m * 16 + l4 * 4;
      #pragma unroll
      for (int n = 0; n < 4; ++n) {
        int gcol = nt * 256 + wn * 64 + n * 16 + l15;
        #pragma unroll
        for (int r = 0; r < 4; ++r)
          kvbK[(size_t)(grow + r) * INNER + gcol] = f2bf(acc[m][n][r]);
      }
    }
  } else {                       // V block -> vT via XOR-swizzled LDS transpose
    int b = m0 >> 12;
    int jblk = m0 & 4095;
    char* Asc = reinterpret_cast<char*>(&As[0][0]);
    char* Bsc = reinterpret_cast<char*>(&Bs[0][0]);
    // write phase: wave wn fills head tile [64 d][256 j]; phys = off^((d&7)<<4)
    char* tb = (wn < 2 ? Asc : Bsc) + (wn & 1) * 32768;
    #pragma unroll
    for (int m = 0; m < 8; ++m) {
      int off = (wm * 128 + m * 16 + l4 * 4) * 2;
      #pragma unroll
      for (int n = 0; n < 4; ++n) {
        int d = n * 16 + l15;
        ushort4 o4;
        o4.x = f2bf(acc[m][n][0]); o4.y = f2bf(acc[m][n][1]);
        o4.z = f2bf(acc[m][n][2]); o4.w = f2bf(acc[m][n][3]);
        *reinterpret_cast<ushort4*>(tb + d * 512 + (off ^ ((d & 7) << 4))) = o4;
      }
    }
    __syncthreads();
    // read phase: stream tiles out as contiguous 16B stores (same XOR)
    #pragma unroll
    for (int e = 0; e < 16; ++e) {
      int lin = e * 8192 + tid * 16;
      int wnn = lin >> 15;
      int rem = lin & 32767;
      int d = rem >> 9;
      int inner = rem & 511;
      short8 v8 = *reinterpret_cast<const short8*>(
          (wnn < 2 ? Asc : Bsc) + (wnn & 1) * 32768 + d * 512 + (inner ^ ((d & 7) << 4)));
      int jl = inner >> 1;
      int hh = (nt - 3) * 4 + wnn;
      unsigned short* dst = vT + ((size_t)(b * NH + hh) * DH + d) * T_ + jblk + jl;
      *reinterpret_cast<short8*>(dst) = v8;
    }
  }
}

// ------- flash attention, bf16 MFMA, K/V dbuf + defer-max + T1 grid --------
__global__ __launch_bounds__(256) void attn_mfma_kernel(
    const unsigned short* __restrict__ qpb, const unsigned short* __restrict__ kvbK,
    const unsigned short* __restrict__ vT,
    float* __restrict__ pO, float* __restrict__ pM, float* __restrict__ pL) {
  int bh = blockIdx.x, kc = blockIdx.y, qt = blockIdx.z;
  int b = bh / NH, h = bh % NH;
  __shared__ __attribute__((aligned(16))) unsigned short Ks[2][4096];
  __shared__ __attribute__((aligned(16))) unsigned short Vs[2][4096];
  __shared__ __attribute__((aligned(16))) unsigned short Ps[4][1024];
  int tid = threadIdx.x;
  int w = tid >> 6, lane = tid & 63;
  int l15 = lane & 15, l4 = lane >> 4;

  short8 qf[2];
  {
    const unsigned short* qb = qpb + (size_t)(qt * 64 + w * 16 + l15) * INNER + h * DH;
    qf[0] = *reinterpret_cast<const short8*>(qb + l4 * 8);
    qf[1] = *reinterpret_cast<const short8*>(qb + 32 + l4 * 8);
  }

  int srow0 = w * 16 + (lane >> 3);
  int srow1 = srow0 + 8;
  int koff0 = (((lane & 7) ^ (srow0 & 7)) << 3);
  int koff1 = (((lane & 7) ^ (srow1 & 7)) << 3);

  const size_t kbase = ((size_t)b * T_) * INNER + h * DH;
  const size_t vbase = ((size_t)bh * DH) * T_;

  auto stageKV = [&](int kt, int d) {
    int j0 = kc * 2048 + kt * 64;
    __builtin_amdgcn_global_load_lds(
        (const __attribute__((address_space(1))) void*)(kvbK + kbase + (size_t)(j0 + srow0) * INNER + koff0),
        (__attribute__((address_space(3))) void*)(&Ks[d][0] + w * 1024 + lane * 8), 16, 0, 0);
    __builtin_amdgcn_global_load_lds(
        (const __attribute__((address_space(1))) void*)(kvbK + kbase + (size_t)(j0 + srow1) * INNER + koff1),
        (__attribute__((address_space(3))) void*)(&Ks[d][0] + w * 1024 + 512 + lane * 8), 16, 0, 0);
    __builtin_amdgcn_global_load_lds(
        (const __attribute__((address_space(1))) void*)(vT + vbase + (size_t)srow0 * T_ + j0 + koff0),
        (__attribute__((address_space(3))) void*)(&Vs[d][0] + w * 1024 + lane * 8), 16, 0, 0);
    __builtin_amdgcn_global_load_lds(
        (const __attribute__((address_space(1))) void*)(vT + vbase + (size_t)srow1 * T_ + j0 + koff1),
        (__attribute__((address_space(3))) void*)(&Vs[d][0] + w * 1024 + 512 + lane * 8), 16, 0, 0);
  };

  f32x4 o[4];
  #pragma unroll
  for (int i = 0; i < 4; ++i) o[i] = (f32x4){0.f, 0.f, 0.f, 0.f};
  float m_run = -1e30f, l_run = 0.f;

  stageKV(0, 0);

  for (int kt = 0; kt < 32; ++kt) {
    int cur = kt & 1;
    if (kt + 1 < 32) {
      stageKV(kt + 1, cur ^ 1);
      asm volatile("s_waitcnt vmcnt(4)" ::: "memory");
    } else {
      asm volatile("s_waitcnt vmcnt(0)" ::: "memory");
    }
    __builtin_amdgcn_s_barrier();
    __builtin_amdgcn_sched_barrier(0);

    const char* Kb = reinterpret_cast<const char*>(&Ks[cur][0]);
    const char* Vb = reinterpret_cast<const char*>(&Vs[cur][0]);

    f32x4 st[4];
    __builtin_amdgcn_s_setprio(1);
    #pragma unroll
    for (int sub = 0; sub < 4; ++sub) {
      st[sub] = (f32x4){0.f, 0.f, 0.f, 0.f};
      #pragma unroll
      for (int hf = 0; hf < 2; ++hf) {
        int row = sub * 16 + l15;
        int byt = row * 128 + (((l4 + 4 * hf) ^ (row & 7)) << 4);
        short8 kf = *reinterpret_cast<const short8*>(Kb + byt);
        st[sub] = __builtin_amdgcn_mfma_f32_16x16x32_bf16(kf, qf[hf], st[sub], 0, 0, 0);
      }
    }
    __builtin_amdgcn_s_setprio(0);

    float tmax = -1e30f;
    #pragma unroll
    for (int sub = 0; sub < 4; ++sub)
      #pragma unroll
      for (int r = 0; r < 4; ++r) tmax = fmaxf(tmax, st[sub][r]);
    tmax = fmaxf(tmax, __shfl_xor(tmax, 16));
    tmax = fmaxf(tmax, __shfl_xor(tmax, 32));

    if (__ballot(tmax > m_run + 8.f)) {
      float m_new = fmaxf(m_run, tmax);
      float alpha = __expf(m_run - m_new);
      float ao[4];
      #pragma unroll
      for (int r = 0; r < 4; ++r) ao[r] = __shfl(alpha, (l4 << 2) | r);
      #pragma unroll
      for (int ds = 0; ds < 4; ++ds)
        #pragma unroll
        for (int r = 0; r < 4; ++r) o[ds][r] *= ao[r];
      l_run *= alpha;
      m_run = m_new;
    }

    float psum = 0.f;
    #pragma unroll
    for (int sub = 0; sub < 4; ++sub) {
      float p0 = __expf(st[sub][0] - m_run);
      float p1 = __expf(st[sub][1] - m_run);
      float p2 = __expf(st[sub][2] - m_run);
      float p3 = __expf(st[sub][3] - m_run);
      psum += (p0 + p1) + (p2 + p3);
      unsigned int u0 = (unsigned int)f2bf(p0) | ((unsigned int)f2bf(p1) << 16);
      unsigned int u1 = (unsigned int)f2bf(p2) | ((unsigned int)f2bf(p3) << 16);
      int slot = (sub * 2 + (l4 >> 1)) ^ (l15 & 7);
      int byt = l15 * 128 + (slot << 4) + (l4 & 1) * 8;
      uint2 uv; uv.x = u0; uv.y = u1;
      *reinterpret_cast<uint2*>(reinterpret_cast<char*>(Ps[w]) + byt) = uv;
    }
    psum += __shfl_xor(psum, 16);
    psum += __shfl_xor(psum, 32);
    l_run += psum;

    short8 pa[2];
    #pragma unroll
    for (int hf = 0; hf < 2; ++hf) {
      int byt = l15 * 128 + ((((hf << 2) + l4) ^ (l15 & 7)) << 4);
      pa[hf] = *reinterpret_cast<const short8*>(reinterpret_cast<const char*>(Ps[w]) + byt);
    }
    __builtin_amdgcn_s_setprio(1);
    #pragma unroll
    for (int ds = 0; ds < 4; ++ds) {
      #pragma unroll
      for (int hf = 0; hf < 2; ++hf) {
        int row = ds * 16 + l15;
        int byt = row * 128 + (((l4 + 4 * hf) ^ (row & 7)) << 4);
        short8 vf = *reinterpret_cast<const short8*>(Vb + byt);
        o[ds] = __builtin_amdgcn_mfma_f32_16x16x32_bf16(pa[hf], vf, o[ds], 0, 0, 0);
      }
    }
    __builtin_amdgcn_s_setprio(0);
    __builtin_amdgcn_s_barrier();
    __builtin_amdgcn_sched_barrier(0);
  }

  int pidx = bh * 2 + kc;
  int qrow0 = qt * 64 + w * 16;
  if (l4 == 0) {
    pM[(size_t)pidx * NQ + qrow0 + l15] = m_run;
    pL[(size_t)pidx * NQ + qrow0 + l15] = l_run;
  }
  #pragma unroll
  for (int ds = 0; ds < 4; ++ds)
    #pragma unroll
    for (int r = 0; r < 4; ++r)
      pO[((size_t)pidx * NQ + qrow0 + l4 * 4 + r) * DH + ds * 16 + l15] = o[ds][r];
}

// ------ fused combine + out GEMM: out = combine(pO,pM,pL) @ WoutT^T --------
__global__ __launch_bounds__(256) void outfuse_kernel(
    const float* __restrict__ pO, const float* __restrict__ pM,
    const float* __restrict__ pL, const unsigned short* __restrict__ WoutT,
    float* __restrict__ out) {
  __shared__ __attribute__((aligned(16))) unsigned short As[128 * 64];
  __shared__ __attribute__((aligned(16))) unsigned short Bs[128 * 64];
  int tid = threadIdx.x;
  int w = tid >> 6, lane = tid & 63;
  int bid = blockIdx.x;                       // 96 blocks, %8==0 -> bijective
  int sw = (bid & 7) * 12 + (bid >> 3);
  int mt = sw / 6, nt = sw % 6;
  int m0 = mt * 128, n0 = nt * 128;

  int srow[4], skoff[4];
  #pragma unroll
  for (int i = 0; i < 4; ++i) {
    int L = w * 4096 + i * 1024 + lane * 16;
    int row = L >> 7;
    int slot = (L >> 4) & 7;
    srow[i] = row;
    skoff[i] = ((slot ^ (row & 7)) << 3);
  }

  f32x4 acc[4][4];
  #pragma unroll
  for (int m = 0; m < 4; ++m)
    #pragma unroll
    for (int n = 0; n < 4; ++n) acc[m][n] = (f32x4){0.f, 0.f, 0.f, 0.f};

  int wr = w >> 1, wc = w & 1;
  int l15 = lane & 15, l4 = lane >> 4;

  for (int t = 0; t < NH; ++t) {              // K-tile == head
    #pragma unroll
    for (int i = 0; i < 4; ++i) {
      int lin = i * 256 + tid;
      int r = lin >> 3, sl = lin & 7;
      int gr = m0 + r;
      int b = gr >> 8, q = gr & 255;
      size_t i0 = ((size_t)(b * NH + t) * 2) * NQ + q;
      size_t i1 = i0 + NQ;
      float m1 = pM[i0], m2 = pM[i1], l1 = pL[i0], l2 = pL[i1];
      float Mx = fmaxf(m1, m2);
      float w1 = __expf(m1 - Mx), w2 = __expf(m2 - Mx);
      float invL = 1.f / (l1 * w1 + l2 * w2);
      w1 *= invL; w2 *= invL;
      const float* p0 = pO + i0 * DH + sl * 8;
      const float* p1 = pO + i1 * DH + sl * 8;
      float4 a0 = *reinterpret_cast<const float4*>(p0);
      float4 a1 = *reinterpret_cast<const float4*>(p0 + 4);
      float4 b0 = *reinterpret_cast<const float4*>(p1);
      float4 b1 = *reinterpret_cast<const float4*>(p1 + 4);
      short8 v8;
      v8[0] = (short)f2bf(a0.x * w1 + b0.x * w2);
      v8[1] = (short)f2bf(a0.y * w1 + b0.y * w2);
      v8[2] = (short)f2bf(a0.z * w1 + b0.z * w2);
      v8[3] = (short)f2bf(a0.w * w1 + b0.w * w2);
      v8[4] = (short)f2bf(a1.x * w1 + b1.x * w2);
      v8[5] = (short)f2bf(a1.y * w1 + b1.y * w2);
      v8[6] = (short)f2bf(a1.z * w1 + b1.z * w2);
      v8[7] = (short)f2bf(a1.w * w1 + b1.w * w2);
      *reinterpret_cast<short8*>(reinterpret_cast<char*>(As) +
                                 r * 128 + ((sl ^ (r & 7)) << 4)) = v8;
    }
    int k0 = t * 64;
    #pragma unroll
    for (int i = 0; i < 4; ++i) {
      __builtin_amdgcn_global_load_lds(
          (const __attribute__((address_space(1))) void*)(WoutT + (size_t)(n0 + srow[i]) * INNER + k0 + skoff[i]),
          (__attribute__((address_space(3))) void*)(Bs + w * 2048 + i * 512 + lane * 8),
          16, 0, 0);
    }
    __syncthreads();
    #pragma unroll
    for (int kh = 0; kh < 2; ++kh) {
      short8 af[4], bf[4];
      #pragma unroll
      for (int m = 0; m < 4; ++m) {
        int row = wr * 64 + m * 16 + l15;
        int byte = row * 128 + (((l4 + 4 * kh) ^ (row & 7)) << 4);
        af[m] = *reinterpret_cast<const short8*>(reinterpret_cast<const char*>(As) + byte);
      }
      #pragma unroll
      for (int n = 0; n < 4; ++n) {
        int row = wc * 64 + n * 16 + l15;
        int byte = row * 128 + (((l4 + 4 * kh) ^ (row & 7)) << 4);
        bf[n] = *reinterpret_cast<const short8*>(reinterpret_cast<const char*>(Bs) + byte);
      }
      #pragma unroll
      for (int m = 0; m < 4; ++m)
        #pragma unroll
        for (int n = 0; n < 4; ++n)
          acc[m][n] = __builtin_amdgcn_mfma_f32_16x16x32_bf16(af[m], bf[n], acc[m][n], 0, 0, 0);
    }
    __syncthreads();
  }

  #pragma unroll
  for (int m = 0; m < 4; ++m) {
    int grow = m0 + wr * 64 + m * 16 + l4 * 4;
    #pragma unroll
    for (int n = 0; n < 4; ++n) {
      int gcol = n0 + wc * 64 + n * 16 + l15;
      #pragma unroll
      for (int r = 0; r < 4; ++r)
        out[(size_t)(grow + r) * DM + gcol] = acc[m][n][r];
    }
  }
}

// ---------------------------------------------------------------------------
extern "C" void kernel_launch(void* const* d_in, const int* in_sizes, int n_in,
                              void* d_out, int out_size, void* d_ws, size_t ws_size,
                              hipStream_t stream) {
  const float* x      = (const float*)d_in[0];
  const float* query  = (const float*)d_in[1];
  const float* ln_q_w = (const float*)d_in[2];
  const float* ln_q_b = (const float*)d_in[3];
  const float* ln_k_w = (const float*)d_in[4];
  const float* ln_k_b = (const float*)d_in[5];
  const float* Wq     = (const float*)d_in[6];
  const float* Wkv    = (const float*)d_in[7];
  const float* Wout   = (const float*)d_in[8];
  float* out = (float*)d_out;

  unsigned short* qpb   = (unsigned short*)d_ws;              // 196608
  unsigned short* xn    = qpb + (size_t)NQ * INNER;           // 33554432
  unsigned short* wkvT  = xn + (size_t)MKV * CD;              // 1572864
  unsigned short* kvbK  = wkvT + (size_t)NKV * CD;            // 25165824
  unsigned short* vT    = kvbK + (size_t)MKV * INNER;         // 25165824
  float* pO    = (float*)(vT + (size_t)MKV * INNER);          // 3145728 f
  float* pM    = pO + (size_t)B_ * NH * 2 * NQ * DH;          // 49152 f
  float* pL    = pM + (size_t)B_ * NH * 2 * NQ;               // 49152 f
  unsigned short* qn    = (unsigned short*)(pL + (size_t)B_ * NH * 2 * NQ);  // 196608
  unsigned short* WqT   = qn + (size_t)NQ * DM;               // 589824
  unsigned short* WoutT = WqT + (size_t)DM * INNER;           // 589824

  hipLaunchKernelGGL(tbw_kernel, dim3(CD / 32, NKV / 32, 3), dim3(256), 0, stream,
                     Wkv, wkvT, Wq, WqT, Wout, WoutT);
  hipLaunchKernelGGL(qln_kernel, dim3(NQ), dim3(256), 0, stream,
                     query, ln_q_w, ln_q_b, qn);
  hipLaunchKernelGGL((gemm128_kernel<0>), dim3((NQ / 128) * (INNER / 128)), dim3(256), 0, stream,
                     qn, WqT, (void*)qpb, INNER, DM, INNER / 128, SCALE, 0);
  hipLaunchKernelGGL(xnorm_kernel, dim3(MKV), dim3(256), 0, stream,
                     x, ln_k_w, ln_k_b, xn);
  hipLaunchKernelGGL(kv_split_kernel, dim3((MKV / KBM) * (NKV / KBN)), dim3(512), 0, stream,
                     xn, wkvT, kvbK, vT);
  hipLaunchKernelGGL(attn_mfma_kernel, dim3(B_ * NH, 2, 4), dim3(256), 0, stream,
                     qpb, kvbK, vT, pO, pM, pL);
  hipLaunchKernelGGL(outfuse_kernel, dim3((B_ * NQ / 128) * (DM / 128)), dim3(256), 0, stream,
                     pO, pM, pL, WoutT, out);
}

// Round 20
// 250.392 us; speedup vs baseline: 1.0520x; 1.0170x over previous
//
#include <hip/hip_runtime.h>
#include <hip/hip_bf16.h>
#include <math.h>

#define B_    8
#define T_    4096
#define CD    1024
#define DM    768
#define NH    12
#define DH    64
#define NQ    256
#define INNER 768
#define NKV   1536
#define MKV   (B_*T_)
#define EPS   1e-5f
#define SCALE 0.125f

typedef __attribute__((ext_vector_type(8))) short short8;
typedef __attribute__((ext_vector_type(4))) float f32x4;

__device__ __forceinline__ unsigned short f2bf(float f) {
  union { __hip_bfloat16 h; unsigned short u; } cv;
  cv.h = __float2bfloat16(f);
  return cv.u;
}
__device__ __forceinline__ float bf2f(unsigned short u) {
  return __uint_as_float(((unsigned int)u) << 16);
}

// ------ merged weight transposes: f32 [SR][SC] -> bf16 [SC][SR], z-indexed --
__global__ __launch_bounds__(256) void tbw_kernel(
    const float* __restrict__ s0, unsigned short* __restrict__ d0,
    const float* __restrict__ s1, unsigned short* __restrict__ d1,
    const float* __restrict__ s2, unsigned short* __restrict__ d2) {
  int z = blockIdx.z;
  const float* src; unsigned short* dst; int SR, SC;
  if (z == 0)      { src = s0; dst = d0; SR = CD;    SC = NKV; }
  else if (z == 1) { src = s1; dst = d1; SR = DM;    SC = INNER; }
  else             { src = s2; dst = d2; SR = INNER; SC = DM; }
  int k0 = blockIdx.x * 32, n0 = blockIdx.y * 32;
  if (k0 >= SR || n0 >= SC) return;
  __shared__ float tile[32][33];
  int tid = threadIdx.x;
  int r = tid >> 3, c4 = (tid & 7) * 4;
  float4 v = *reinterpret_cast<const float4*>(&src[(size_t)(k0 + r) * SC + n0 + c4]);
  tile[r][c4 + 0] = v.x; tile[r][c4 + 1] = v.y; tile[r][c4 + 2] = v.z; tile[r][c4 + 3] = v.w;
  __syncthreads();
  ushort4 o4;
  o4.x = f2bf(tile[c4 + 0][r]);
  o4.y = f2bf(tile[c4 + 1][r]);
  o4.z = f2bf(tile[c4 + 2][r]);
  o4.w = f2bf(tile[c4 + 3][r]);
  *reinterpret_cast<ushort4*>(&dst[(size_t)(n0 + r) * SR + k0 + c4]) = o4;
}

// ----------------------------- LN(query) -> bf16 ---------------------------
__global__ __launch_bounds__(256) void qln_kernel(
    const float* __restrict__ query, const float* __restrict__ lnw,
    const float* __restrict__ lnb, unsigned short* __restrict__ qn) {
  int row = blockIdx.x, tid = threadIdx.x;
  __shared__ float rbuf[256];
  const float* qr = query + (size_t)row * DM;
  float v0 = qr[tid], v1 = qr[tid + 256], v2 = qr[tid + 512];
  rbuf[tid] = v0 + v1 + v2;
  __syncthreads();
  for (int o = 128; o > 0; o >>= 1) { if (tid < o) rbuf[tid] += rbuf[tid + o]; __syncthreads(); }
  float mean = rbuf[0] * (1.f / 768.f);
  __syncthreads();
  float d0 = v0 - mean, d1 = v1 - mean, d2 = v2 - mean;
  rbuf[tid] = d0 * d0 + d1 * d1 + d2 * d2;
  __syncthreads();
  for (int o = 128; o > 0; o >>= 1) { if (tid < o) rbuf[tid] += rbuf[tid + o]; __syncthreads(); }
  float var = rbuf[0] * (1.f / 768.f);
  float rs = rsqrtf(var + EPS);
  unsigned short* dst = qn + (size_t)row * DM;
  dst[tid]       = f2bf(d0 * rs * lnw[tid]       + lnb[tid]);
  dst[tid + 256] = f2bf(d1 * rs * lnw[tid + 256] + lnb[tid + 256]);
  dst[tid + 512] = f2bf(d2 * rs * lnw[tid + 512] + lnb[tid + 512]);
}

// ---------------------------- LN(x) -> bf16, fused stats + normalize -------
__global__ __launch_bounds__(256) void xnorm_kernel(
    const float* __restrict__ x, const float* __restrict__ lnw,
    const float* __restrict__ lnb, unsigned short* __restrict__ xn) {
  int row = blockIdx.x, tid = threadIdx.x;
  float4 v = reinterpret_cast<const float4*>(x + (size_t)row * CD)[tid];
  float s  = v.x + v.y + v.z + v.w;
  float ss = v.x * v.x + v.y * v.y + v.z * v.z + v.w * v.w;
  #pragma unroll
  for (int o = 32; o > 0; o >>= 1) { s += __shfl_down(s, o); ss += __shfl_down(ss, o); }
  __shared__ float sm[8];
  int wid = tid >> 6, lane = tid & 63;
  if (lane == 0) { sm[wid] = s; sm[4 + wid] = ss; }
  __syncthreads();
  float S  = sm[0] + sm[1] + sm[2] + sm[3];
  float SS = sm[4] + sm[5] + sm[6] + sm[7];
  float m  = S * (1.f / 1024.f);
  float var = SS * (1.f / 1024.f) - m * m;
  float rs = rsqrtf(fmaxf(var, 0.f) + EPS);
  float4 wv = reinterpret_cast<const float4*>(lnw)[tid];
  float4 bv = reinterpret_cast<const float4*>(lnb)[tid];
  ushort4 o4;
  o4.x = f2bf((v.x - m) * rs * wv.x + bv.x);
  o4.y = f2bf((v.y - m) * rs * wv.y + bv.y);
  o4.z = f2bf((v.z - m) * rs * wv.z + bv.z);
  o4.w = f2bf((v.w - m) * rs * wv.w + bv.w);
  reinterpret_cast<ushort4*>(xn + (size_t)row * CD)[tid] = o4;
}

// ----------- generic 128x128 bf16 MFMA GEMM: C = A[M][K] @ Bt[N][K]^T ------
template <int MODE>
__global__ __launch_bounds__(256) void gemm128_kernel(
    const unsigned short* __restrict__ A, const unsigned short* __restrict__ Bt,
    void* __restrict__ Cout, int N, int K, int nN, float scale, int swz) {
  __shared__ __attribute__((aligned(16))) unsigned short As[128 * 64];
  __shared__ __attribute__((aligned(16))) unsigned short Bs[128 * 64];
  int tid = threadIdx.x;
  int w = tid >> 6, lane = tid & 63;
  int bid = blockIdx.x;
  int sw = swz ? ((bid & 7) * ((int)gridDim.x >> 3) + (bid >> 3)) : bid;
  int mt = sw / nN, nt = sw % nN;
  int m0 = mt * 128, n0 = nt * 128;

  int srow[4], skoff[4];
  #pragma unroll
  for (int i = 0; i < 4; ++i) {
    int L = w * 4096 + i * 1024 + lane * 16;
    int row = L >> 7;
    int slot = (L >> 4) & 7;
    srow[i] = row;
    skoff[i] = ((slot ^ (row & 7)) << 3);
  }

  f32x4 acc[4][4];
  #pragma unroll
  for (int m = 0; m < 4; ++m)
    #pragma unroll
    for (int n = 0; n < 4; ++n) acc[m][n] = (f32x4){0.f, 0.f, 0.f, 0.f};

  int wr = w >> 1, wc = w & 1;
  int l15 = lane & 15, l4 = lane >> 4;

  for (int t = 0; t < K / 64; ++t) {
    int k0 = t * 64;
    #pragma unroll
    for (int i = 0; i < 4; ++i) {
      __builtin_amdgcn_global_load_lds(
          (const __attribute__((address_space(1))) void*)(A + (size_t)(m0 + srow[i]) * K + k0 + skoff[i]),
          (__attribute__((address_space(3))) void*)(As + w * 2048 + i * 512 + lane * 8),
          16, 0, 0);
    }
    #pragma unroll
    for (int i = 0; i < 4; ++i) {
      __builtin_amdgcn_global_load_lds(
          (const __attribute__((address_space(1))) void*)(Bt + (size_t)(n0 + srow[i]) * K + k0 + skoff[i]),
          (__attribute__((address_space(3))) void*)(Bs + w * 2048 + i * 512 + lane * 8),
          16, 0, 0);
    }
    __syncthreads();
    #pragma unroll
    for (int kh = 0; kh < 2; ++kh) {
      short8 af[4], bf[4];
      #pragma unroll
      for (int m = 0; m < 4; ++m) {
        int row = wr * 64 + m * 16 + l15;
        int byte = row * 128 + (((l4 + 4 * kh) ^ (row & 7)) << 4);
        af[m] = *reinterpret_cast<const short8*>(reinterpret_cast<const char*>(As) + byte);
      }
      #pragma unroll
      for (int n = 0; n < 4; ++n) {
        int row = wc * 64 + n * 16 + l15;
        int byte = row * 128 + (((l4 + 4 * kh) ^ (row & 7)) << 4);
        bf[n] = *reinterpret_cast<const short8*>(reinterpret_cast<const char*>(Bs) + byte);
      }
      #pragma unroll
      for (int m = 0; m < 4; ++m)
        #pragma unroll
        for (int n = 0; n < 4; ++n)
          acc[m][n] = __builtin_amdgcn_mfma_f32_16x16x32_bf16(af[m], bf[n], acc[m][n], 0, 0, 0);
    }
    __syncthreads();
  }

  #pragma unroll
  for (int m = 0; m < 4; ++m) {
    int grow = m0 + wr * 64 + m * 16 + l4 * 4;
    #pragma unroll
    for (int n = 0; n < 4; ++n) {
      int gcol = n0 + wc * 64 + n * 16 + l15;
      #pragma unroll
      for (int r = 0; r < 4; ++r) {
        if (MODE == 0)
          ((unsigned short*)Cout)[(size_t)(grow + r) * N + gcol] = f2bf(acc[m][n][r] * scale);
        else
          ((float*)Cout)[(size_t)(grow + r) * N + gcol] = acc[m][n][r];
      }
    }
  }
}

// -------- kv GEMM: 256x256, 8 waves, dbuf, 2-phase core --------------------
// K-blocks (nt<3) write dense kvbK; V-blocks (nt>=3) transpose through
// XOR-swizzled LDS (phys = off ^ ((d&7)<<4), both sides) -> contiguous 16B.
#define KBM 256
#define KBN 256
#define KBK 64
__global__ __launch_bounds__(512, 2) void kv_split_kernel(
    const unsigned short* __restrict__ xn, const unsigned short* __restrict__ wkvT,
    unsigned short* __restrict__ kvbK, unsigned short* __restrict__ vT) {
  __shared__ __attribute__((aligned(16))) unsigned short As[2][KBM * KBK];  // 64 KB
  __shared__ __attribute__((aligned(16))) unsigned short Bs[2][KBN * KBK];  // 64 KB
  int tid = threadIdx.x;
  int w = tid >> 6, lane = tid & 63;
  int wm = w >> 2, wn = w & 3;
  int l15 = lane & 15, l4 = lane >> 4;

  int bid = blockIdx.x;                      // 768 blocks, %8==0 -> bijective
  int sw = (bid & 7) * 96 + (bid >> 3);
  int mt = sw / (NKV / KBN), nt = sw % (NKV / KBN);
  int m0 = mt * KBM, n0 = nt * KBN;

  int srow[4], koff[4];
  #pragma unroll
  for (int i = 0; i < 4; ++i) {
    int r = i * 64 + (tid >> 3);
    srow[i] = r;
    koff[i] = (((tid & 7) ^ (r & 7)) << 3);
  }

  f32x4 acc[8][4];
  #pragma unroll
  for (int m = 0; m < 8; ++m)
    #pragma unroll
    for (int n = 0; n < 4; ++n) acc[m][n] = (f32x4){0.f, 0.f, 0.f, 0.f};

  #pragma unroll
  for (int i = 0; i < 4; ++i) {
    __builtin_amdgcn_global_load_lds(
        (const __attribute__((address_space(1))) void*)(xn + (size_t)(m0 + srow[i]) * CD + koff[i]),
        (__attribute__((address_space(3))) void*)(&As[0][0] + i * 4096 + tid * 8), 16, 0, 0);
    __builtin_amdgcn_global_load_lds(
        (const __attribute__((address_space(1))) void*)(wkvT + (size_t)(n0 + srow[i]) * CD + koff[i]),
        (__attribute__((address_space(3))) void*)(&Bs[0][0] + i * 4096 + tid * 8), 16, 0, 0);
  }
  __syncthreads();

  for (int t = 0; t < CD / KBK; ++t) {
    int cur = t & 1;
    if (t + 1 < CD / KBK) {
      int k0 = (t + 1) * KBK;
      #pragma unroll
      for (int i = 0; i < 4; ++i) {
        __builtin_amdgcn_global_load_lds(
            (const __attribute__((address_space(1))) void*)(xn + (size_t)(m0 + srow[i]) * CD + k0 + koff[i]),
            (__attribute__((address_space(3))) void*)(&As[cur ^ 1][0] + i * 4096 + tid * 8), 16, 0, 0);
        __builtin_amdgcn_global_load_lds(
            (const __attribute__((address_space(1))) void*)(wkvT + (size_t)(n0 + srow[i]) * CD + k0 + koff[i]),
            (__attribute__((address_space(3))) void*)(&Bs[cur ^ 1][0] + i * 4096 + tid * 8), 16, 0, 0);
      }
    }
    const char* Ab = reinterpret_cast<const char*>(&As[cur][0]);
    const char* Bb = reinterpret_cast<const char*>(&Bs[cur][0]);
    #pragma unroll
    for (int kh = 0; kh < 2; ++kh) {
      short8 bf[4];
      #pragma unroll
      for (int n = 0; n < 4; ++n) {
        int row = wn * 64 + n * 16 + l15;
        int byt = row * 128 + (((kh * 4 + l4) ^ (row & 7)) << 4);
        bf[n] = *reinterpret_cast<const short8*>(Bb + byt);
      }
      #pragma unroll
      for (int m = 0; m < 8; ++m) {
        int row = wm * 128 + m * 16 + l15;
        int byt = row * 128 + (((kh * 4 + l4) ^ (row & 7)) << 4);
        short8 af = *reinterpret_cast<const short8*>(Ab + byt);
        #pragma unroll
        for (int n = 0; n < 4; ++n)
          acc[m][n] = __builtin_amdgcn_mfma_f32_16x16x32_bf16(af, bf[n], acc[m][n], 0, 0, 0);
      }
    }
    __syncthreads();
  }

  if (nt < 3) {                                        // K block -> kvbK dense
    #pragma unroll
    for (int m = 0; m < 8; ++m) {
      int grow = m0 + wm * 128 + m * 16 + l4 * 4;
      #pragma unroll
      for (int n = 0; n < 4; ++n) {
        int gcol = nt * 256 + wn * 64 + n * 16 + l15;
        #pragma unroll
        for (int r = 0; r < 4; ++r)
          kvbK[(size_t)(grow + r) * INNER + gcol] = f2bf(acc[m][n][r]);
      }
    }
  } else {                       // V block -> vT via XOR-swizzled LDS transpose
    int b = m0 >> 12;
    int jblk = m0 & 4095;
    char* Asc = reinterpret_cast<char*>(&As[0][0]);
    char* Bsc = reinterpret_cast<char*>(&Bs[0][0]);
    char* tb = (wn < 2 ? Asc : Bsc) + (wn & 1) * 32768;
    #pragma unroll
    for (int m = 0; m < 8; ++m) {
      int off = (wm * 128 + m * 16 + l4 * 4) * 2;
      #pragma unroll
      for (int n = 0; n < 4; ++n) {
        int d = n * 16 + l15;
        ushort4 o4;
        o4.x = f2bf(acc[m][n][0]); o4.y = f2bf(acc[m][n][1]);
        o4.z = f2bf(acc[m][n][2]); o4.w = f2bf(acc[m][n][3]);
        *reinterpret_cast<ushort4*>(tb + d * 512 + (off ^ ((d & 7) << 4))) = o4;
      }
    }
    __syncthreads();
    #pragma unroll
    for (int e = 0; e < 16; ++e) {
      int lin = e * 8192 + tid * 16;
      int wnn = lin >> 15;
      int rem = lin & 32767;
      int d = rem >> 9;
      int inner = rem & 511;
      short8 v8 = *reinterpret_cast<const short8*>(
          (wnn < 2 ? Asc : Bsc) + (wnn & 1) * 32768 + d * 512 + (inner ^ ((d & 7) << 4)));
      int jl = inner >> 1;
      int hh = (nt - 3) * 4 + wnn;
      unsigned short* dst = vT + ((size_t)(b * NH + hh) * DH + d) * T_ + jblk + jl;
      *reinterpret_cast<short8*>(dst) = v8;
    }
  }
}

// ------- flash attention, bf16 MFMA, dbuf + defer-max + T1 grid ------------
// Partial O now stored as bf16 (halves pO HBM round-trip).
__global__ __launch_bounds__(256) void attn_mfma_kernel(
    const unsigned short* __restrict__ qpb, const unsigned short* __restrict__ kvbK,
    const unsigned short* __restrict__ vT,
    unsigned short* __restrict__ pOb, float* __restrict__ pM, float* __restrict__ pL) {
  int bh = blockIdx.x, kc = blockIdx.y, qt = blockIdx.z;
  int b = bh / NH, h = bh % NH;
  __shared__ __attribute__((aligned(16))) unsigned short Ks[2][4096];
  __shared__ __attribute__((aligned(16))) unsigned short Vs[2][4096];
  __shared__ __attribute__((aligned(16))) unsigned short Ps[4][1024];
  int tid = threadIdx.x;
  int w = tid >> 6, lane = tid & 63;
  int l15 = lane & 15, l4 = lane >> 4;

  short8 qf[2];
  {
    const unsigned short* qb = qpb + (size_t)(qt * 64 + w * 16 + l15) * INNER + h * DH;
    qf[0] = *reinterpret_cast<const short8*>(qb + l4 * 8);
    qf[1] = *reinterpret_cast<const short8*>(qb + 32 + l4 * 8);
  }

  int srow0 = w * 16 + (lane >> 3);
  int srow1 = srow0 + 8;
  int koff0 = (((lane & 7) ^ (srow0 & 7)) << 3);
  int koff1 = (((lane & 7) ^ (srow1 & 7)) << 3);

  const size_t kbase = ((size_t)b * T_) * INNER + h * DH;
  const size_t vbase = ((size_t)bh * DH) * T_;

  auto stageKV = [&](int kt, int d) {
    int j0 = kc * 2048 + kt * 64;
    __builtin_amdgcn_global_load_lds(
        (const __attribute__((address_space(1))) void*)(kvbK + kbase + (size_t)(j0 + srow0) * INNER + koff0),
        (__attribute__((address_space(3))) void*)(&Ks[d][0] + w * 1024 + lane * 8), 16, 0, 0);
    __builtin_amdgcn_global_load_lds(
        (const __attribute__((address_space(1))) void*)(kvbK + kbase + (size_t)(j0 + srow1) * INNER + koff1),
        (__attribute__((address_space(3))) void*)(&Ks[d][0] + w * 1024 + 512 + lane * 8), 16, 0, 0);
    __builtin_amdgcn_global_load_lds(
        (const __attribute__((address_space(1))) void*)(vT + vbase + (size_t)srow0 * T_ + j0 + koff0),
        (__attribute__((address_space(3))) void*)(&Vs[d][0] + w * 1024 + lane * 8), 16, 0, 0);
    __builtin_amdgcn_global_load_lds(
        (const __attribute__((address_space(1))) void*)(vT + vbase + (size_t)srow1 * T_ + j0 + koff1),
        (__attribute__((address_space(3))) void*)(&Vs[d][0] + w * 1024 + 512 + lane * 8), 16, 0, 0);
  };

  f32x4 o[4];
  #pragma unroll
  for (int i = 0; i < 4; ++i) o[i] = (f32x4){0.f, 0.f, 0.f, 0.f};
  float m_run = -1e30f, l_run = 0.f;

  stageKV(0, 0);

  for (int kt = 0; kt < 32; ++kt) {
    int cur = kt & 1;
    if (kt + 1 < 32) {
      stageKV(kt + 1, cur ^ 1);
      asm volatile("s_waitcnt vmcnt(4)" ::: "memory");
    } else {
      asm volatile("s_waitcnt vmcnt(0)" ::: "memory");
    }
    __builtin_amdgcn_s_barrier();
    __builtin_amdgcn_sched_barrier(0);

    const char* Kb = reinterpret_cast<const char*>(&Ks[cur][0]);
    const char* Vb = reinterpret_cast<const char*>(&Vs[cur][0]);

    f32x4 st[4];
    __builtin_amdgcn_s_setprio(1);
    #pragma unroll
    for (int sub = 0; sub < 4; ++sub) {
      st[sub] = (f32x4){0.f, 0.f, 0.f, 0.f};
      #pragma unroll
      for (int hf = 0; hf < 2; ++hf) {
        int row = sub * 16 + l15;
        int byt = row * 128 + (((l4 + 4 * hf) ^ (row & 7)) << 4);
        short8 kf = *reinterpret_cast<const short8*>(Kb + byt);
        st[sub] = __builtin_amdgcn_mfma_f32_16x16x32_bf16(kf, qf[hf], st[sub], 0, 0, 0);
      }
    }
    __builtin_amdgcn_s_setprio(0);

    float tmax = -1e30f;
    #pragma unroll
    for (int sub = 0; sub < 4; ++sub)
      #pragma unroll
      for (int r = 0; r < 4; ++r) tmax = fmaxf(tmax, st[sub][r]);
    tmax = fmaxf(tmax, __shfl_xor(tmax, 16));
    tmax = fmaxf(tmax, __shfl_xor(tmax, 32));

    if (__ballot(tmax > m_run + 8.f)) {
      float m_new = fmaxf(m_run, tmax);
      float alpha = __expf(m_run - m_new);
      float ao[4];
      #pragma unroll
      for (int r = 0; r < 4; ++r) ao[r] = __shfl(alpha, (l4 << 2) | r);
      #pragma unroll
      for (int ds = 0; ds < 4; ++ds)
        #pragma unroll
        for (int r = 0; r < 4; ++r) o[ds][r] *= ao[r];
      l_run *= alpha;
      m_run = m_new;
    }

    float psum = 0.f;
    #pragma unroll
    for (int sub = 0; sub < 4; ++sub) {
      float p0 = __expf(st[sub][0] - m_run);
      float p1 = __expf(st[sub][1] - m_run);
      float p2 = __expf(st[sub][2] - m_run);
      float p3 = __expf(st[sub][3] - m_run);
      psum += (p0 + p1) + (p2 + p3);
      unsigned int u0 = (unsigned int)f2bf(p0) | ((unsigned int)f2bf(p1) << 16);
      unsigned int u1 = (unsigned int)f2bf(p2) | ((unsigned int)f2bf(p3) << 16);
      int slot = (sub * 2 + (l4 >> 1)) ^ (l15 & 7);
      int byt = l15 * 128 + (slot << 4) + (l4 & 1) * 8;
      uint2 uv; uv.x = u0; uv.y = u1;
      *reinterpret_cast<uint2*>(reinterpret_cast<char*>(Ps[w]) + byt) = uv;
    }
    psum += __shfl_xor(psum, 16);
    psum += __shfl_xor(psum, 32);
    l_run += psum;

    short8 pa[2];
    #pragma unroll
    for (int hf = 0; hf < 2; ++hf) {
      int byt = l15 * 128 + ((((hf << 2) + l4) ^ (l15 & 7)) << 4);
      pa[hf] = *reinterpret_cast<const short8*>(reinterpret_cast<const char*>(Ps[w]) + byt);
    }
    __builtin_amdgcn_s_setprio(1);
    #pragma unroll
    for (int ds = 0; ds < 4; ++ds) {
      #pragma unroll
      for (int hf = 0; hf < 2; ++hf) {
        int row = ds * 16 + l15;
        int byt = row * 128 + (((l4 + 4 * hf) ^ (row & 7)) << 4);
        short8 vf = *reinterpret_cast<const short8*>(Vb + byt);
        o[ds] = __builtin_amdgcn_mfma_f32_16x16x32_bf16(pa[hf], vf, o[ds], 0, 0, 0);
      }
    }
    __builtin_amdgcn_s_setprio(0);
    __builtin_amdgcn_s_barrier();
    __builtin_amdgcn_sched_barrier(0);
  }

  int pidx = bh * 2 + kc;
  int qrow0 = qt * 64 + w * 16;
  if (l4 == 0) {
    pM[(size_t)pidx * NQ + qrow0 + l15] = m_run;
    pL[(size_t)pidx * NQ + qrow0 + l15] = l_run;
  }
  #pragma unroll
  for (int ds = 0; ds < 4; ++ds)
    #pragma unroll
    for (int r = 0; r < 4; ++r)
      pOb[((size_t)pidx * NQ + qrow0 + l4 * 4 + r) * DH + ds * 16 + l15] = f2bf(o[ds][r]);
}

// ------ fused combine + out GEMM: out = combine(pOb,pM,pL) @ WoutT^T -------
__global__ __launch_bounds__(256) void outfuse_kernel(
    const unsigned short* __restrict__ pOb, const float* __restrict__ pM,
    const float* __restrict__ pL, const unsigned short* __restrict__ WoutT,
    float* __restrict__ out) {
  __shared__ __attribute__((aligned(16))) unsigned short As[128 * 64];
  __shared__ __attribute__((aligned(16))) unsigned short Bs[128 * 64];
  int tid = threadIdx.x;
  int w = tid >> 6, lane = tid & 63;
  int bid = blockIdx.x;                       // 96 blocks, %8==0 -> bijective
  int sw = (bid & 7) * 12 + (bid >> 3);
  int mt = sw / 6, nt = sw % 6;
  int m0 = mt * 128, n0 = nt * 128;

  int srow[4], skoff[4];
  #pragma unroll
  for (int i = 0; i < 4; ++i) {
    int L = w * 4096 + i * 1024 + lane * 16;
    int row = L >> 7;
    int slot = (L >> 4) & 7;
    srow[i] = row;
    skoff[i] = ((slot ^ (row & 7)) << 3);
  }

  f32x4 acc[4][4];
  #pragma unroll
  for (int m = 0; m < 4; ++m)
    #pragma unroll
    for (int n = 0; n < 4; ++n) acc[m][n] = (f32x4){0.f, 0.f, 0.f, 0.f};

  int wr = w >> 1, wc = w & 1;
  int l15 = lane & 15, l4 = lane >> 4;

  for (int t = 0; t < NH; ++t) {              // K-tile == head
    #pragma unroll
    for (int i = 0; i < 4; ++i) {
      int lin = i * 256 + tid;
      int r = lin >> 3, sl = lin & 7;
      int gr = m0 + r;
      int b = gr >> 8, q = gr & 255;
      size_t i0 = ((size_t)(b * NH + t) * 2) * NQ + q;
      size_t i1 = i0 + NQ;
      float m1 = pM[i0], m2 = pM[i1], l1 = pL[i0], l2 = pL[i1];
      float Mx = fmaxf(m1, m2);
      float w1 = __expf(m1 - Mx), w2 = __expf(m2 - Mx);
      float invL = 1.f / (l1 * w1 + l2 * w2);
      w1 *= invL; w2 *= invL;
      short8 s0 = *reinterpret_cast<const short8*>(pOb + i0 * DH + sl * 8);
      short8 s1 = *reinterpret_cast<const short8*>(pOb + i1 * DH + sl * 8);
      short8 v8;
      #pragma unroll
      for (int k = 0; k < 8; ++k)
        v8[k] = (short)f2bf(bf2f((unsigned short)s0[k]) * w1 +
                            bf2f((unsigned short)s1[k]) * w2);
      *reinterpret_cast<short8*>(reinterpret_cast<char*>(As) +
                                 r * 128 + ((sl ^ (r & 7)) << 4)) = v8;
    }
    int k0 = t * 64;
    #pragma unroll
    for (int i = 0; i < 4; ++i) {
      __builtin_amdgcn_global_load_lds(
          (const __attribute__((address_space(1))) void*)(WoutT + (size_t)(n0 + srow[i]) * INNER + k0 + skoff[i]),
          (__attribute__((address_space(3))) void*)(Bs + w * 2048 + i * 512 + lane * 8),
          16, 0, 0);
    }
    __syncthreads();
    #pragma unroll
    for (int kh = 0; kh < 2; ++kh) {
      short8 af[4], bf[4];
      #pragma unroll
      for (int m = 0; m < 4; ++m) {
        int row = wr * 64 + m * 16 + l15;
        int byte = row * 128 + (((l4 + 4 * kh) ^ (row & 7)) << 4);
        af[m] = *reinterpret_cast<const short8*>(reinterpret_cast<const char*>(As) + byte);
      }
      #pragma unroll
      for (int n = 0; n < 4; ++n) {
        int row = wc * 64 + n * 16 + l15;
        int byte = row * 128 + (((l4 + 4 * kh) ^ (row & 7)) << 4);
        bf[n] = *reinterpret_cast<const short8*>(reinterpret_cast<const char*>(Bs) + byte);
      }
      #pragma unroll
      for (int m = 0; m < 4; ++m)
        #pragma unroll
        for (int n = 0; n < 4; ++n)
          acc[m][n] = __builtin_amdgcn_mfma_f32_16x16x32_bf16(af[m], bf[n], acc[m][n], 0, 0, 0);
    }
    __syncthreads();
  }

  #pragma unroll
  for (int m = 0; m < 4; ++m) {
    int grow = m0 + wr * 64 + m * 16 + l4 * 4;
    #pragma unroll
    for (int n = 0; n < 4; ++n) {
      int gcol = n0 + wc * 64 + n * 16 + l15;
      #pragma unroll
      for (int r = 0; r < 4; ++r)
        out[(size_t)(grow + r) * DM + gcol] = acc[m][n][r];
    }
  }
}

// ---------------------------------------------------------------------------
extern "C" void kernel_launch(void* const* d_in, const int* in_sizes, int n_in,
                              void* d_out, int out_size, void* d_ws, size_t ws_size,
                              hipStream_t stream) {
  const float* x      = (const float*)d_in[0];
  const float* query  = (const float*)d_in[1];
  const float* ln_q_w = (const float*)d_in[2];
  const float* ln_q_b = (const float*)d_in[3];
  const float* ln_k_w = (const float*)d_in[4];
  const float* ln_k_b = (const float*)d_in[5];
  const float* Wq     = (const float*)d_in[6];
  const float* Wkv    = (const float*)d_in[7];
  const float* Wout   = (const float*)d_in[8];
  float* out = (float*)d_out;

  unsigned short* qpb   = (unsigned short*)d_ws;              // 196608
  unsigned short* xn    = qpb + (size_t)NQ * INNER;           // 33554432
  unsigned short* wkvT  = xn + (size_t)MKV * CD;              // 1572864
  unsigned short* kvbK  = wkvT + (size_t)NKV * CD;            // 25165824
  unsigned short* vT    = kvbK + (size_t)MKV * INNER;         // 25165824
  unsigned short* pOb   = vT + (size_t)MKV * INNER;           // 3145728 bf16
  float* pM    = (float*)(pOb + (size_t)B_ * NH * 2 * NQ * DH);  // 49152 f
  float* pL    = pM + (size_t)B_ * NH * 2 * NQ;               // 49152 f
  unsigned short* qn    = (unsigned short*)(pL + (size_t)B_ * NH * 2 * NQ);  // 196608
  unsigned short* WqT   = qn + (size_t)NQ * DM;               // 589824
  unsigned short* WoutT = WqT + (size_t)DM * INNER;           // 589824

  hipLaunchKernelGGL(tbw_kernel, dim3(CD / 32, NKV / 32, 3), dim3(256), 0, stream,
                     Wkv, wkvT, Wq, WqT, Wout, WoutT);
  hipLaunchKernelGGL(qln_kernel, dim3(NQ), dim3(256), 0, stream,
                     query, ln_q_w, ln_q_b, qn);
  hipLaunchKernelGGL((gemm128_kernel<0>), dim3((NQ / 128) * (INNER / 128)), dim3(256), 0, stream,
                     qn, WqT, (void*)qpb, INNER, DM, INNER / 128, SCALE, 0);
  hipLaunchKernelGGL(xnorm_kernel, dim3(MKV), dim3(256), 0, stream,
                     x, ln_k_w, ln_k_b, xn);
  hipLaunchKernelGGL(kv_split_kernel, dim3((MKV / KBM) * (NKV / KBN)), dim3(512), 0, stream,
                     xn, wkvT, kvbK, vT);
  hipLaunchKernelGGL(attn_mfma_kernel, dim3(B_ * NH, 2, 4), dim3(256), 0, stream,
                     qpb, kvbK, vT, pOb, pM, pL);
  hipLaunchKernelGGL(outfuse_kernel, dim3((B_ * NQ / 128) * (DM / 128)), dim3(256), 0, stream,
                     pOb, pM, pL, WoutT, out);
}